// Round 12
// baseline (591.234 us; speedup 1.0000x reference)
//
#include <hip/hip_runtime.h>

typedef float fx4 __attribute__((ext_vector_type(4)));
typedef float f32x4 __attribute__((ext_vector_type(4)));
typedef unsigned short us4v __attribute__((ext_vector_type(4)));
typedef unsigned short us8 __attribute__((ext_vector_type(8)));
typedef __bf16 bf8 __attribute__((ext_vector_type(8)));

static __device__ __forceinline__ fx4 ld4(const float* p) {
    return *reinterpret_cast<const fx4*>(p);
}
static __device__ __forceinline__ void st4(float* p, fx4 v) {
    *reinterpret_cast<fx4*>(p) = v;
}
static __device__ __forceinline__ unsigned short f2bf(float f) {
    union { float f; unsigned int i; } x; x.f = f;
    unsigned int r = x.i + 0x7FFF + ((x.i >> 16) & 1);   // RNE
    return (unsigned short)(r >> 16);
}
static __device__ __forceinline__ float bf2f(unsigned int u) {
    union { unsigned int i; float f; } x; x.i = u << 16; return x.f;
}
static __device__ __forceinline__ us4v pk4(f32x4 v) {
    us4v u;
    #pragma unroll
    for (int j = 0; j < 4; ++j) u[j] = f2bf(v[j]);
    return u;
}

// LDS XOR swizzle (T2): 16B chunk j of row r lives at chunk (j ^ (r&7)).
// Row stride = K1 shorts exactly (no pad). For any 16 consecutive rows the
// same chunk lands on 8 distinct 16B slots -> all 32 banks, 2-way max (free).
static __device__ __forceinline__ int swz(int row, int chunk, int K1shorts) {
    return row * K1shorts + ((chunk ^ (row & 7)) << 3);
}

// Swapped-operand MFMA (W-fragment first): lane holds 4 consecutive output
// cols of one row: row(within 16-blk)=lane&15, col quad = (lane>>4)*4.
static __device__ __forceinline__ f32x4 mfma16(us8 a, us8 b, f32x4 c) {
    return __builtin_amdgcn_mfma_f32_16x16x32_bf16(
        __builtin_bit_cast(bf8, a), __builtin_bit_cast(bf8, b), c, 0, 0, 0);
}

// Load A fragment (2 m-tiles) for k-step kk from global. AF32: fp32->bf16.
template <int K1, bool AF32>
static __device__ __forceinline__ void loadA(
    const void* __restrict__ Av, int row0, int ar, int ak, int kk, int M, us8 a[2])
{
    #pragma unroll
    for (int m = 0; m < 2; ++m) {
        int row = row0 + m * 16 + ar;
        us8 t = 0;
        if (row < M) {
            if (AF32) {
                const float* ap = (const float*)Av + (size_t)row * K1 + kk * 32 + ak;
                fx4 x0 = ld4(ap), x1 = ld4(ap + 4);
                #pragma unroll
                for (int j = 0; j < 4; ++j) { t[j] = f2bf(x0[j]); t[4 + j] = f2bf(x1[j]); }
            } else {
                t = *reinterpret_cast<const us8*>(
                    (const unsigned short*)Av + (size_t)row * K1 + kk * 32 + ak);
            }
        }
        a[m] = t;
    }
}

// ---------------- MFMA GEMM: W staged in LDS (swizzled), per-block tile ------
// Out[M][128] = A[M][K1] @ W[K1][128]; Wt[n][k] = W[k][n] (bf16).
// XMODE: out = acc + resid[r][col] + deg[r]*bias[col]
template <int K1, bool AF32, bool BIAS, bool RELU, bool OUTF, bool OUTB, bool XMODE>
__global__ __launch_bounds__(256) void mfma_gemm(
    const void* __restrict__ Av, const unsigned short* __restrict__ Wt,
    const float* __restrict__ bias,
    float* __restrict__ outF, unsigned short* __restrict__ outB,
    const float* __restrict__ resid, const int* __restrict__ startp, int M)
{
    __shared__ unsigned short Ws[128 * K1];
    const int tid = threadIdx.x;
    const int lane = tid & 63;
    const int wv = tid >> 6;
    const int row0 = blockIdx.x * 128 + wv * 32;

    constexpr int CH = K1 / 8;                    // 16B chunks per row
    for (int i = tid; i < 128 * CH; i += 256) {
        int r = i / CH, c8 = i % CH;
        *reinterpret_cast<us8*>(&Ws[swz(r, c8, K1)]) =
            *reinterpret_cast<const us8*>(&Wt[(size_t)r * K1 + (c8 << 3)]);
    }
    __syncthreads();

    const int ar = lane & 15;
    const int q = lane >> 4;
    const int ak = q * 8;

    f32x4 acc[2][8];
    #pragma unroll
    for (int m = 0; m < 2; ++m)
        #pragma unroll
        for (int nt = 0; nt < 8; ++nt) acc[m][nt] = {0.f, 0.f, 0.f, 0.f};

    #pragma unroll
    for (int kk = 0; kk < K1 / 32; ++kk) {
        us8 a[2];
        loadA<K1, AF32>(Av, row0, ar, ak, kk, M, a);
        const int chunk = kk * 4 + q;
        #pragma unroll
        for (int nt = 0; nt < 8; ++nt) {
            int brow = nt * 16 + ar;
            us8 b = *reinterpret_cast<const us8*>(&Ws[swz(brow, chunk, K1)]);
            acc[0][nt] = mfma16(b, a[0], acc[0][nt]);
            acc[1][nt] = mfma16(b, a[1], acc[1][nt]);
        }
    }

    #pragma unroll
    for (int m = 0; m < 2; ++m) {
        int r = row0 + m * 16 + (lane & 15);
        if (r >= M) continue;
        float deg = 0.f;
        if (XMODE) deg = (float)(startp[r + 1] - startp[r]);
        #pragma unroll
        for (int nt = 0; nt < 8; ++nt) {
            int c0 = nt * 16 + q * 4;
            f32x4 o = acc[m][nt];
            if (XMODE) {
                fx4 bb = ld4(bias + c0);
                fx4 rr = ld4(resid + (size_t)r * 128 + c0);
                #pragma unroll
                for (int j = 0; j < 4; ++j) o[j] += rr[j] + deg * bb[j];
            } else if (BIAS) {
                fx4 bb = ld4(bias + c0);
                #pragma unroll
                for (int j = 0; j < 4; ++j) o[j] += bb[j];
            }
            if (RELU) {
                #pragma unroll
                for (int j = 0; j < 4; ++j) o[j] = fmaxf(o[j], 0.f);
            }
            if (OUTF) st4(outF + (size_t)r * 128 + c0, o);
            if (OUTB) *reinterpret_cast<us4v*>(&outB[(size_t)r * 128 + c0]) = pk4(o);
        }
    }
}

// ---- fused 2-layer MLP: out = relu(A@W1+b1)@W2 + b2 (K=128), swizzled LDS ---
template <bool AF32, bool OUTF, bool OUTB>
__global__ __launch_bounds__(256) void mfma_mlp(
    const void* __restrict__ Av, const unsigned short* __restrict__ W1t,
    const float* __restrict__ b1, const unsigned short* __restrict__ W2t,
    const float* __restrict__ b2,
    float* __restrict__ outF, unsigned short* __restrict__ outB, int M)
{
    __shared__ unsigned short Ws1[128 * 128];   // W1, later reused as H tile
    __shared__ unsigned short Ws2[128 * 128];
    const int tid = threadIdx.x;
    const int lane = tid & 63;
    const int wv = tid >> 6;
    const int row0 = blockIdx.x * 128 + wv * 32;

    for (int i = tid; i < 128 * 16; i += 256) {
        int r = i >> 4, c8 = i & 15;
        *reinterpret_cast<us8*>(&Ws1[swz(r, c8, 128)]) =
            *reinterpret_cast<const us8*>(&W1t[(size_t)r * 128 + (c8 << 3)]);
        *reinterpret_cast<us8*>(&Ws2[swz(r, c8, 128)]) =
            *reinterpret_cast<const us8*>(&W2t[(size_t)r * 128 + (c8 << 3)]);
    }
    __syncthreads();

    const int ar = lane & 15;
    const int q = lane >> 4;
    const int ak = q * 8;

    f32x4 acc[2][8];
    #pragma unroll
    for (int m = 0; m < 2; ++m)
        #pragma unroll
        for (int nt = 0; nt < 8; ++nt) acc[m][nt] = {0.f, 0.f, 0.f, 0.f};

    #pragma unroll
    for (int kk = 0; kk < 4; ++kk) {
        us8 a[2];
        loadA<128, AF32>(Av, row0, ar, ak, kk, M, a);
        const int chunk = kk * 4 + q;
        #pragma unroll
        for (int nt = 0; nt < 8; ++nt) {
            int brow = nt * 16 + ar;
            us8 b = *reinterpret_cast<const us8*>(&Ws1[swz(brow, chunk, 128)]);
            acc[0][nt] = mfma16(b, a[0], acc[0][nt]);
            acc[1][nt] = mfma16(b, a[1], acc[1][nt]);
        }
    }
    __syncthreads();    // all waves done reading W1 before overwrite

    // write H (bf16) into Ws1 rows wv*32..+32, swizzled (8B within 16B chunk)
    #pragma unroll
    for (int m = 0; m < 2; ++m) {
        int lrow = wv * 32 + m * 16 + (lane & 15);
        #pragma unroll
        for (int nt = 0; nt < 8; ++nt) {
            int c0 = nt * 16 + q * 4;               // shorts
            int chunk = c0 >> 3, inner = c0 & 7;    // inner = 0 or 4
            fx4 bb = ld4(b1 + c0);
            f32x4 o = acc[m][nt];
            #pragma unroll
            for (int j = 0; j < 4; ++j) o[j] = fmaxf(o[j] + bb[j], 0.f);
            *reinterpret_cast<us4v*>(&Ws1[swz(lrow, chunk, 128) + inner]) = pk4(o);
        }
    }
    __syncthreads();

    f32x4 acc2[2][8];
    #pragma unroll
    for (int m = 0; m < 2; ++m)
        #pragma unroll
        for (int nt = 0; nt < 8; ++nt) acc2[m][nt] = {0.f, 0.f, 0.f, 0.f};

    #pragma unroll
    for (int kk = 0; kk < 4; ++kk) {
        const int chunk = kk * 4 + q;
        us8 a[2];
        #pragma unroll
        for (int m = 0; m < 2; ++m) {
            int arow = wv * 32 + m * 16 + ar;
            a[m] = *reinterpret_cast<const us8*>(&Ws1[swz(arow, chunk, 128)]);
        }
        #pragma unroll
        for (int nt = 0; nt < 8; ++nt) {
            int brow = nt * 16 + ar;
            us8 b = *reinterpret_cast<const us8*>(&Ws2[swz(brow, chunk, 128)]);
            acc2[0][nt] = mfma16(b, a[0], acc2[0][nt]);
            acc2[1][nt] = mfma16(b, a[1], acc2[1][nt]);
        }
    }

    #pragma unroll
    for (int m = 0; m < 2; ++m) {
        int r = row0 + m * 16 + (lane & 15);
        if (r >= M) continue;
        #pragma unroll
        for (int nt = 0; nt < 8; ++nt) {
            int c0 = nt * 16 + q * 4;
            fx4 bb = ld4(b2 + c0);
            f32x4 o = acc2[m][nt];
            #pragma unroll
            for (int j = 0; j < 4; ++j) o[j] += bb[j];
            if (OUTF) st4(outF + (size_t)r * 128 + c0, o);
            if (OUTB) *reinterpret_cast<us4v*>(&outB[(size_t)r * 128 + c0]) = pk4(o);
        }
    }
}

// ---- dual-output GEMM: [O1|O2] = A[M][128] @ [Wa|Wb]; Wt 256 rows, swizzled -
// AF32: A fp32 (else bf16). BIAS2: add b0[col] to O1, b1[col] to O2.
template <bool AF32, bool BIAS2>
__global__ __launch_bounds__(256) void mfma_gemm_dual(
    const void* __restrict__ Av, const unsigned short* __restrict__ Wt,
    const float* __restrict__ b0, const float* __restrict__ b1,
    unsigned short* __restrict__ out1, unsigned short* __restrict__ out2, int M)
{
    __shared__ unsigned short Ws[256 * 128];
    const int tid = threadIdx.x;
    const int lane = tid & 63;
    const int wv = tid >> 6;
    const int row0 = blockIdx.x * 128 + wv * 32;

    for (int i = tid; i < 256 * 16; i += 256) {
        int r = i >> 4, c8 = i & 15;
        *reinterpret_cast<us8*>(&Ws[swz(r, c8, 128)]) =
            *reinterpret_cast<const us8*>(&Wt[(size_t)r * 128 + (c8 << 3)]);
    }
    __syncthreads();

    const int ar = lane & 15;
    const int q = lane >> 4;
    const int ak = q * 8;

    f32x4 acc[2][16];
    #pragma unroll
    for (int m = 0; m < 2; ++m)
        #pragma unroll
        for (int nt = 0; nt < 16; ++nt) acc[m][nt] = {0.f, 0.f, 0.f, 0.f};

    #pragma unroll
    for (int kk = 0; kk < 4; ++kk) {
        us8 a[2];
        loadA<128, AF32>(Av, row0, ar, ak, kk, M, a);
        const int chunk = kk * 4 + q;
        #pragma unroll
        for (int nt = 0; nt < 16; ++nt) {
            int brow = nt * 16 + ar;
            us8 b = *reinterpret_cast<const us8*>(&Ws[swz(brow, chunk, 128)]);
            acc[0][nt] = mfma16(b, a[0], acc[0][nt]);
            acc[1][nt] = mfma16(b, a[1], acc[1][nt]);
        }
    }

    #pragma unroll
    for (int m = 0; m < 2; ++m) {
        int r = row0 + m * 16 + (lane & 15);
        if (r >= M) continue;
        #pragma unroll
        for (int nt = 0; nt < 16; ++nt) {
            int c0 = (nt & 7) * 16 + q * 4;
            unsigned short* o = (nt < 8) ? out1 : out2;
            f32x4 v = acc[m][nt];
            if (BIAS2) {
                const float* bl = (nt < 8) ? b0 : b1;
                fx4 bb = ld4(bl + c0);
                #pragma unroll
                for (int j = 0; j < 4; ++j) v[j] += bb[j];
            }
            *reinterpret_cast<us4v*>(&o[(size_t)r * 128 + c0]) = pk4(v);
        }
    }
}

// ---------------- fp32 helper GEMM for the tiny weight-fold (M=128) ----------
__global__ __launch_bounds__(256) void gemm128_kernel(
    const float* __restrict__ X, const float* __restrict__ W,
    float* __restrict__ Out, int M)
{
    __shared__ float Xs[64 * 132];
    const int tid = threadIdx.x;
    const int row0 = blockIdx.x * 64;

    for (int i = tid; i < 64 * 32; i += 256) {
        int r = i >> 5, c = (i & 31) * 4;
        fx4 v = {0.f, 0.f, 0.f, 0.f};
        int gr = row0 + r;
        if (gr < M) v = ld4(X + (size_t)gr * 128 + c);
        st4(&Xs[r * 132 + c], v);
    }
    __syncthreads();

    const int ty = tid >> 4, tx = tid & 15;
    fx4 acc[4][2];
    #pragma unroll
    for (int r = 0; r < 4; ++r) { acc[r][0] = 0.f; acc[r][1] = 0.f; }
    for (int k = 0; k < 128; k += 4) {
        fx4 xr[4];
        #pragma unroll
        for (int r = 0; r < 4; ++r) xr[r] = ld4(&Xs[(ty * 4 + r) * 132 + k]);
        #pragma unroll
        for (int kk = 0; kk < 4; ++kk) {
            fx4 wa = ld4(W + (size_t)(k + kk) * 128 + tx * 8);
            fx4 wb = ld4(W + (size_t)(k + kk) * 128 + tx * 8 + 4);
            #pragma unroll
            for (int r = 0; r < 4; ++r) {
                acc[r][0] += xr[r][kk] * wa;
                acc[r][1] += xr[r][kk] * wb;
            }
        }
    }
    #pragma unroll
    for (int r = 0; r < 4; ++r) {
        int gr = row0 + ty * 4 + r;
        if (gr < M) {
            st4(Out + (size_t)gr * 128 + tx * 8, acc[r][0]);
            st4(Out + (size_t)gr * 128 + tx * 8 + 4, acc[r][1]);
        }
    }
}

// ---------------- weight prep ------------------------------------------------
struct TJob { const float* src; unsigned short* dst; int K; };
struct TJobs { TJob j[16]; };

__global__ __launch_bounds__(256) void transpose_kernel(TJobs jobs) {
    TJob t = jobs.j[blockIdx.x];
    int total = 128 * t.K;
    for (int i = threadIdx.x; i < total; i += 256) {
        int n = i / t.K, k = i - n * t.K;
        t.dst[(size_t)n * t.K + k] = f2bf(t.src[(size_t)k * 128 + n]);
    }
}

__global__ __launch_bounds__(128) void bep_kernel(
    const float* __restrict__ ee_b2, const float* __restrict__ ml_w1,
    const float* __restrict__ ml_b1, float* __restrict__ bep)
{
    int l = blockIdx.x, n = threadIdx.x;
    const float* W1b = ml_w1 + (size_t)l * 384 * 128 + 128 * 128;
    float s = ml_b1[(size_t)l * 128 + n];
    for (int k = 0; k < 128; ++k) s += ee_b2[k] * W1b[(size_t)k * 128 + n];
    bep[(size_t)l * 128 + n] = s;
}

// ---------------- CSR build --------------------------------------------------
__global__ __launch_bounds__(256) void csr_hist_kernel(
    const int* __restrict__ el, int* __restrict__ cnt, int NE)
{
    int e = blockIdx.x * 256 + threadIdx.x;
    if (e < NE) {
        atomicAdd(&cnt[el[2 * (size_t)e + 1]], 1);
        atomicAdd(&cnt[el[2 * (size_t)e]], 1);
    }
}

__global__ __launch_bounds__(256) void scan_p1_kernel(
    const int* __restrict__ cnt, int* __restrict__ bsum, int NN)
{
    __shared__ int red[256];
    const int t = threadIdx.x;
    int i = blockIdx.x * 256 + t;
    red[t] = (i < NN) ? cnt[i] : 0;
    __syncthreads();
    for (int off = 128; off > 0; off >>= 1) {
        if (t < off) red[t] += red[t + off];
        __syncthreads();
    }
    if (t == 0) bsum[blockIdx.x] = red[0];
}

__global__ __launch_bounds__(256) void scan_p2_kernel(
    int* __restrict__ bsum, int* __restrict__ startp, int nb, int NN)
{
    __shared__ int part[256];
    const int t = threadIdx.x;
    int v = (t < nb) ? bsum[t] : 0;
    part[t] = v;
    __syncthreads();
    for (int off = 1; off < 256; off <<= 1) {
        int u = (t >= off) ? part[t - off] : 0;
        __syncthreads();
        part[t] += u;
        __syncthreads();
    }
    if (t < nb) bsum[t] = part[t] - v;
    if (t == 255) startp[NN] = part[255];
}

__global__ __launch_bounds__(256) void scan_p3_kernel(
    int* __restrict__ cnt, const int* __restrict__ bsum,
    int* __restrict__ startp, int NN)
{
    __shared__ int part[256];
    const int t = threadIdx.x;
    int i = blockIdx.x * 256 + t;
    int v = (i < NN) ? cnt[i] : 0;
    part[t] = v;
    __syncthreads();
    for (int off = 1; off < 256; off <<= 1) {
        int u = (t >= off) ? part[t - off] : 0;
        __syncthreads();
        part[t] += u;
        __syncthreads();
    }
    if (i < NN) {
        startp[i] = bsum[blockIdx.x] + part[t] - v;
        cnt[i] = 0;
    }
}

__global__ __launch_bounds__(256) void csr_fill_kernel(
    const int* __restrict__ el, const int* __restrict__ startp,
    int* __restrict__ cursor, int2* __restrict__ inc, int NE)
{
    int e = blockIdx.x * 256 + threadIdx.x;
    if (e < NE) {
        int s = el[2 * (size_t)e], d = el[2 * (size_t)e + 1];
        int p = startp[d] + atomicAdd(&cursor[d], 1);
        inc[p] = make_int2(s, e);
        int q = startp[s] + atomicAdd(&cursor[s], 1);
        inc[q] = make_int2(d, e);
    }
}

// ---------------- gather: S[n] = sum_j relu(P1[o_j] + Ep[e_j] + P3[n]) -------
__global__ __launch_bounds__(256) void gather_kernel(
    const unsigned short* __restrict__ P1bf, const unsigned short* __restrict__ P3bf,
    const unsigned short* __restrict__ Ep, const int2* __restrict__ inc,
    const int* __restrict__ startp, unsigned short* __restrict__ S, int M)
{
    const int tid = threadIdx.x;
    const int lane = tid & 63;
    const int n = blockIdx.x * 4 + (tid >> 6);
    if (n >= M) return;
    const int slot = lane >> 4;
    const int c = (lane & 15) * 8;

    float p3[8], acc[8];
    us8 u3 = *reinterpret_cast<const us8*>(&P3bf[(size_t)n * 128 + c]);
    #pragma unroll
    for (int i = 0; i < 8; ++i) {
        p3[i] = bf2f((unsigned int)(unsigned short)u3[i]);
        acc[i] = 0.f;
    }

    const int j1 = startp[n + 1];
    int j = startp[n] + slot;
    int2 oe = (j < j1) ? inc[j] : make_int2(0, 0);
    while (j < j1) {
        int jn = j + 4;
        int2 oen = (jn < j1) ? inc[jn] : make_int2(0, 0);
        us8 u1 = *reinterpret_cast<const us8*>(&P1bf[(size_t)oe.x * 128 + c]);
        us8 ue = *reinterpret_cast<const us8*>(&Ep[(size_t)oe.y * 128 + c]);
        #pragma unroll
        for (int i = 0; i < 8; ++i)
            acc[i] += fmaxf(p3[i] + bf2f((unsigned int)(unsigned short)u1[i])
                                  + bf2f((unsigned int)(unsigned short)ue[i]), 0.f);
        j = jn; oe = oen;
    }

    #pragma unroll
    for (int i = 0; i < 8; ++i) {
        acc[i] += __shfl_xor(acc[i], 16, 64);
        acc[i] += __shfl_xor(acc[i], 32, 64);
    }
    if (slot == 0) {
        us8 pk;
        #pragma unroll
        for (int i = 0; i < 8; ++i) pk[i] = f2bf(acc[i]);
        *reinterpret_cast<us8*>(&S[(size_t)n * 128 + c]) = pk;
    }
}

// ---------------- host launch ------------------------------------------------
extern "C" void kernel_launch(void* const* d_in, const int* in_sizes, int n_in,
                              void* d_out, int out_size, void* d_ws, size_t ws_size,
                              hipStream_t stream) {
    const float* node_f    = (const float*)d_in[0];
    const int*   edge_list = (const int*)d_in[1];
    const float* edge_f    = (const float*)d_in[2];
    const float* ne_w1 = (const float*)d_in[4];
    const float* ne_b1 = (const float*)d_in[5];
    const float* ne_w2 = (const float*)d_in[6];
    const float* ne_b2 = (const float*)d_in[7];
    const float* ee_w1 = (const float*)d_in[8];
    const float* ee_b1 = (const float*)d_in[9];
    const float* ee_w2 = (const float*)d_in[10];
    const float* ee_b2 = (const float*)d_in[11];
    const float* ml_w1 = (const float*)d_in[12];
    const float* ml_b1 = (const float*)d_in[13];
    const float* ml_w2 = (const float*)d_in[14];
    const float* ml_b2 = (const float*)d_in[15];
    const float* agg_w1 = (const float*)d_in[16];
    const float* agg_b1 = (const float*)d_in[17];
    const float* agg_w2 = (const float*)d_in[18];
    const float* agg_b2 = (const float*)d_in[19];

    const int NN = in_sizes[0] / 128;
    const int NE = in_sizes[1] / 2;
    const int n_layers = in_sizes[12] / (384 * 128);

    char* p = (char*)d_ws;
    auto alloc = [&](size_t bytes) -> void* {
        void* r = (void*)p;
        p += (bytes + 255) & ~(size_t)255;
        return r;
    };
    float* node_emb = (float*)alloc((size_t)NN * 128 * 4);
    unsigned short* P1bf = (unsigned short*)alloc((size_t)NN * 128 * 2);
    unsigned short* P3bf = (unsigned short*)alloc((size_t)NN * 128 * 2);
    unsigned short* bufS = (unsigned short*)alloc((size_t)NN * 128 * 2);
    unsigned short* H_edge = (unsigned short*)alloc((size_t)NE * 128 * 2);
    unsigned short* Ep0 = (unsigned short*)alloc((size_t)NE * 128 * 2);
    unsigned short* Ep1 = (unsigned short*)alloc((size_t)NE * 128 * 2);
    unsigned short* ne_w1t = (unsigned short*)alloc(128 * 128 * 2);
    unsigned short* ne_w2t = (unsigned short*)alloc(128 * 128 * 2);
    unsigned short* ee_w1t = (unsigned short*)alloc(128 * 64 * 2);
    unsigned short* aw1t = (unsigned short*)alloc(128 * 128 * 2);
    unsigned short* aw2t = (unsigned short*)alloc(128 * 128 * 2);
    unsigned short* Wepct = (unsigned short*)alloc(256 * 128 * 2);  // [Wep0^T; Wep1^T]
    unsigned short* W13t[2], *W2t[2];
    float* Wepf[2];
    for (int l = 0; l < 2; ++l) {
        W13t[l] = (unsigned short*)alloc(256 * 128 * 2);
        W2t[l]  = (unsigned short*)alloc(128 * 128 * 2);
        Wepf[l] = (float*)alloc(128 * 128 * 4);
    }
    float* bep = (float*)alloc((size_t)2 * 128 * 4);
    int* cnt = (int*)alloc((size_t)NN * 4);
    int* startp = (int*)alloc((size_t)(NN + 1) * 4);
    int* bsum = (int*)alloc(256 * 4);
    int2* inc = (int2*)alloc((size_t)2 * NE * 8);
    size_t need = (size_t)(p - (char*)d_ws);
    if (ws_size < need) return;

    dim3 blk(256);
    const int gM_N = (NN + 127) / 128;
    const int gM_E = (NE + 127) / 128;
    const int gE256 = (NE + 255) / 256;
    const int nbScan = (NN + 255) / 256;

    // ---- weight prep ----
    for (int l = 0; l < n_layers && l < 2; ++l) {
        const float* W1b = ml_w1 + (size_t)l * 384 * 128 + 128 * 128;
        gemm128_kernel<<<2, blk, 0, stream>>>(ee_w2, W1b, Wepf[l], 128);
    }
    {
        TJobs jobs{};
        int nj = 0;
        jobs.j[nj++] = {ne_w1, ne_w1t, 128};
        jobs.j[nj++] = {ne_w2, ne_w2t, 128};
        jobs.j[nj++] = {ee_w1, ee_w1t, 64};
        jobs.j[nj++] = {agg_w1, aw1t, 128};
        jobs.j[nj++] = {agg_w2, aw2t, 128};
        for (int l = 0; l < n_layers && l < 2; ++l) {
            jobs.j[nj++] = {ml_w1 + (size_t)l * 384 * 128, W13t[l], 128};
            jobs.j[nj++] = {ml_w1 + (size_t)l * 384 * 128 + 256 * 128, W13t[l] + 128 * 128, 128};
            jobs.j[nj++] = {ml_w2 + (size_t)l * 128 * 128, W2t[l], 128};
        }
        jobs.j[nj++] = {Wepf[0], Wepct, 128};
        jobs.j[nj++] = {Wepf[(n_layers > 1) ? 1 : 0], Wepct + 128 * 128, 128};
        transpose_kernel<<<nj, blk, 0, stream>>>(jobs);
    }
    bep_kernel<<<n_layers, 128, 0, stream>>>(ee_b2, ml_w1, ml_b1, bep);

    // ---- encoders ----
    mfma_mlp<true, true, false><<<gM_N, blk, 0, stream>>>(
        node_f, ne_w1t, ne_b1, ne_w2t, ne_b2, node_emb, nullptr, NN);
    // H_edge = relu(edge_f @ ee_w1 + ee_b1) -> bf16
    mfma_gemm<64, true, true, true, false, true, false><<<gM_E, blk, 0, stream>>>(
        edge_f, ee_w1t, ee_b1, nullptr, H_edge, nullptr, nullptr, NE);
    // [Ep0|Ep1] = H_edge @ [Wep0|Wep1] + [bep0|bep1]  — one pass over H_edge
    mfma_gemm_dual<false, true><<<gM_E, blk, 0, stream>>>(
        H_edge, Wepct, bep, bep + ((n_layers > 1) ? 128 : 0), Ep0, Ep1, NE);

    // ---- CSR incidence ----
    hipMemsetAsync(cnt, 0, (size_t)NN * sizeof(int), stream);
    csr_hist_kernel<<<gE256, blk, 0, stream>>>(edge_list, cnt, NE);
    scan_p1_kernel<<<nbScan, blk, 0, stream>>>(cnt, bsum, NN);
    scan_p2_kernel<<<1, blk, 0, stream>>>(bsum, startp, nbScan, NN);
    scan_p3_kernel<<<nbScan, blk, 0, stream>>>(cnt, bsum, startp, NN);
    csr_fill_kernel<<<gE256, blk, 0, stream>>>(edge_list, startp, cnt, inc, NE);

    float* out = (float*)d_out;
    for (int l = 0; l < n_layers && l < 2; ++l) {
        // [P1|P3] = node_emb @ [W1a|W1c]
        mfma_gemm_dual<true, false><<<gM_N, blk, 0, stream>>>(
            node_emb, W13t[l], nullptr, nullptr, P1bf, P3bf, NN);
        // S = gather-sum of relu'd hiddens -> bufS
        gather_kernel<<<(NN + 3) / 4, blk, 0, stream>>>(
            P1bf, P3bf, (l == 0) ? Ep0 : Ep1, inc, startp, bufS, NN);
        // X = node_emb + S@W2 + deg*b2 -> P1bf (bf16)
        mfma_gemm<128, false, true, false, false, true, true><<<gM_N, blk, 0, stream>>>(
            bufS, W2t[l], ml_b2 + (size_t)l * 128, nullptr, P1bf, node_emb, startp, NN);
        // out = mlp(X; aw1,ab1,aw2,ab2)
        float* dst = (l == n_layers - 1) ? out : node_emb;
        mfma_mlp<false, true, false><<<gM_N, blk, 0, stream>>>(
            P1bf, aw1t, agg_b1, aw2t, agg_b2, dst, nullptr, NN);
    }
}

// Round 13
// 577.743 us; speedup vs baseline: 1.0234x; 1.0234x over previous
//
#include <hip/hip_runtime.h>

typedef float fx4 __attribute__((ext_vector_type(4)));
typedef float f32x4 __attribute__((ext_vector_type(4)));
typedef unsigned short us4v __attribute__((ext_vector_type(4)));
typedef unsigned short us8 __attribute__((ext_vector_type(8)));
typedef __bf16 bf8 __attribute__((ext_vector_type(8)));

static __device__ __forceinline__ fx4 ld4(const float* p) {
    return *reinterpret_cast<const fx4*>(p);
}
static __device__ __forceinline__ void st4(float* p, fx4 v) {
    *reinterpret_cast<fx4*>(p) = v;
}
static __device__ __forceinline__ unsigned short f2bf(float f) {
    union { float f; unsigned int i; } x; x.f = f;
    unsigned int r = x.i + 0x7FFF + ((x.i >> 16) & 1);   // RNE
    return (unsigned short)(r >> 16);
}
static __device__ __forceinline__ float bf2f(unsigned int u) {
    union { unsigned int i; float f; } x; x.i = u << 16; return x.f;
}
static __device__ __forceinline__ us4v pk4(f32x4 v) {
    us4v u;
    #pragma unroll
    for (int j = 0; j < 4; ++j) u[j] = f2bf(v[j]);
    return u;
}

// LDS XOR swizzle: 16B chunk j of row r at chunk (j ^ (r&7)); row stride = K1.
static __device__ __forceinline__ int swz(int row, int chunk, int K1shorts) {
    return row * K1shorts + ((chunk ^ (row & 7)) << 3);
}

// Swapped-operand MFMA (W-fragment first): lane holds 4 consecutive output
// cols of one row: row(within 16-blk)=lane&15, col quad = (lane>>4)*4.
static __device__ __forceinline__ f32x4 mfma16(us8 a, us8 b, f32x4 c) {
    return __builtin_amdgcn_mfma_f32_16x16x32_bf16(
        __builtin_bit_cast(bf8, a), __builtin_bit_cast(bf8, b), c, 0, 0, 0);
}

// Load A fragment (2 m-tiles) for k-step kk from global. AF32: fp32->bf16.
template <int K1, bool AF32>
static __device__ __forceinline__ void loadA(
    const void* __restrict__ Av, int row0, int ar, int ak, int kk, int M, us8 a[2])
{
    #pragma unroll
    for (int m = 0; m < 2; ++m) {
        int row = row0 + m * 16 + ar;
        us8 t = 0;
        if (row < M) {
            if (AF32) {
                const float* ap = (const float*)Av + (size_t)row * K1 + kk * 32 + ak;
                fx4 x0 = ld4(ap), x1 = ld4(ap + 4);
                #pragma unroll
                for (int j = 0; j < 4; ++j) { t[j] = f2bf(x0[j]); t[4 + j] = f2bf(x1[j]); }
            } else {
                t = *reinterpret_cast<const us8*>(
                    (const unsigned short*)Av + (size_t)row * K1 + kk * 32 + ak);
            }
        }
        a[m] = t;
    }
}

// ---------------- MFMA GEMM: W staged in LDS (swizzled), per-block tile ------
// Out[M][128] = A[M][K1] @ W[K1][128]; Wt[n][k] = W[k][n] (bf16).
// XMODE: out = acc + resid[r][col] + deg[r]*bias[col]
template <int K1, bool AF32, bool BIAS, bool RELU, bool OUTF, bool OUTB, bool XMODE>
__global__ __launch_bounds__(256) void mfma_gemm(
    const void* __restrict__ Av, const unsigned short* __restrict__ Wt,
    const float* __restrict__ bias,
    float* __restrict__ outF, unsigned short* __restrict__ outB,
    const float* __restrict__ resid, const int* __restrict__ startp, int M)
{
    __shared__ unsigned short Ws[128 * K1];
    const int tid = threadIdx.x;
    const int lane = tid & 63;
    const int wv = tid >> 6;
    const int row0 = blockIdx.x * 128 + wv * 32;

    constexpr int CH = K1 / 8;
    for (int i = tid; i < 128 * CH; i += 256) {
        int r = i / CH, c8 = i % CH;
        *reinterpret_cast<us8*>(&Ws[swz(r, c8, K1)]) =
            *reinterpret_cast<const us8*>(&Wt[(size_t)r * K1 + (c8 << 3)]);
    }
    __syncthreads();

    const int ar = lane & 15;
    const int q = lane >> 4;
    const int ak = q * 8;

    f32x4 acc[2][8];
    #pragma unroll
    for (int m = 0; m < 2; ++m)
        #pragma unroll
        for (int nt = 0; nt < 8; ++nt) acc[m][nt] = {0.f, 0.f, 0.f, 0.f};

    #pragma unroll
    for (int kk = 0; kk < K1 / 32; ++kk) {
        us8 a[2];
        loadA<K1, AF32>(Av, row0, ar, ak, kk, M, a);
        const int chunk = kk * 4 + q;
        #pragma unroll
        for (int nt = 0; nt < 8; ++nt) {
            int brow = nt * 16 + ar;
            us8 b = *reinterpret_cast<const us8*>(&Ws[swz(brow, chunk, K1)]);
            acc[0][nt] = mfma16(b, a[0], acc[0][nt]);
            acc[1][nt] = mfma16(b, a[1], acc[1][nt]);
        }
    }

    #pragma unroll
    for (int m = 0; m < 2; ++m) {
        int r = row0 + m * 16 + (lane & 15);
        if (r >= M) continue;
        float deg = 0.f;
        if (XMODE) deg = (float)(startp[r + 1] - startp[r]);
        #pragma unroll
        for (int nt = 0; nt < 8; ++nt) {
            int c0 = nt * 16 + q * 4;
            f32x4 o = acc[m][nt];
            if (XMODE) {
                fx4 bb = ld4(bias + c0);
                fx4 rr = ld4(resid + (size_t)r * 128 + c0);
                #pragma unroll
                for (int j = 0; j < 4; ++j) o[j] += rr[j] + deg * bb[j];
            } else if (BIAS) {
                fx4 bb = ld4(bias + c0);
                #pragma unroll
                for (int j = 0; j < 4; ++j) o[j] += bb[j];
            }
            if (RELU) {
                #pragma unroll
                for (int j = 0; j < 4; ++j) o[j] = fmaxf(o[j], 0.f);
            }
            if (OUTF) st4(outF + (size_t)r * 128 + c0, o);
            if (OUTB) *reinterpret_cast<us4v*>(&outB[(size_t)r * 128 + c0]) = pk4(o);
        }
    }
}

// ---- fused 2-layer MLP: out = relu(A@W1+b1)@W2 + b2 (K=128), swizzled LDS ---
template <bool AF32, bool OUTF, bool OUTB>
__global__ __launch_bounds__(256) void mfma_mlp(
    const void* __restrict__ Av, const unsigned short* __restrict__ W1t,
    const float* __restrict__ b1, const unsigned short* __restrict__ W2t,
    const float* __restrict__ b2,
    float* __restrict__ outF, unsigned short* __restrict__ outB, int M)
{
    __shared__ unsigned short Ws1[128 * 128];   // W1, later reused as H tile
    __shared__ unsigned short Ws2[128 * 128];
    const int tid = threadIdx.x;
    const int lane = tid & 63;
    const int wv = tid >> 6;
    const int row0 = blockIdx.x * 128 + wv * 32;

    for (int i = tid; i < 128 * 16; i += 256) {
        int r = i >> 4, c8 = i & 15;
        *reinterpret_cast<us8*>(&Ws1[swz(r, c8, 128)]) =
            *reinterpret_cast<const us8*>(&W1t[(size_t)r * 128 + (c8 << 3)]);
        *reinterpret_cast<us8*>(&Ws2[swz(r, c8, 128)]) =
            *reinterpret_cast<const us8*>(&W2t[(size_t)r * 128 + (c8 << 3)]);
    }
    __syncthreads();

    const int ar = lane & 15;
    const int q = lane >> 4;
    const int ak = q * 8;

    f32x4 acc[2][8];
    #pragma unroll
    for (int m = 0; m < 2; ++m)
        #pragma unroll
        for (int nt = 0; nt < 8; ++nt) acc[m][nt] = {0.f, 0.f, 0.f, 0.f};

    #pragma unroll
    for (int kk = 0; kk < 4; ++kk) {
        us8 a[2];
        loadA<128, AF32>(Av, row0, ar, ak, kk, M, a);
        const int chunk = kk * 4 + q;
        #pragma unroll
        for (int nt = 0; nt < 8; ++nt) {
            int brow = nt * 16 + ar;
            us8 b = *reinterpret_cast<const us8*>(&Ws1[swz(brow, chunk, 128)]);
            acc[0][nt] = mfma16(b, a[0], acc[0][nt]);
            acc[1][nt] = mfma16(b, a[1], acc[1][nt]);
        }
    }
    __syncthreads();

    #pragma unroll
    for (int m = 0; m < 2; ++m) {
        int lrow = wv * 32 + m * 16 + (lane & 15);
        #pragma unroll
        for (int nt = 0; nt < 8; ++nt) {
            int c0 = nt * 16 + q * 4;
            int chunk = c0 >> 3, inner = c0 & 7;
            fx4 bb = ld4(b1 + c0);
            f32x4 o = acc[m][nt];
            #pragma unroll
            for (int j = 0; j < 4; ++j) o[j] = fmaxf(o[j] + bb[j], 0.f);
            *reinterpret_cast<us4v*>(&Ws1[swz(lrow, chunk, 128) + inner]) = pk4(o);
        }
    }
    __syncthreads();

    f32x4 acc2[2][8];
    #pragma unroll
    for (int m = 0; m < 2; ++m)
        #pragma unroll
        for (int nt = 0; nt < 8; ++nt) acc2[m][nt] = {0.f, 0.f, 0.f, 0.f};

    #pragma unroll
    for (int kk = 0; kk < 4; ++kk) {
        const int chunk = kk * 4 + q;
        us8 a[2];
        #pragma unroll
        for (int m = 0; m < 2; ++m) {
            int arow = wv * 32 + m * 16 + ar;
            a[m] = *reinterpret_cast<const us8*>(&Ws1[swz(arow, chunk, 128)]);
        }
        #pragma unroll
        for (int nt = 0; nt < 8; ++nt) {
            int brow = nt * 16 + ar;
            us8 b = *reinterpret_cast<const us8*>(&Ws2[swz(brow, chunk, 128)]);
            acc2[0][nt] = mfma16(b, a[0], acc2[0][nt]);
            acc2[1][nt] = mfma16(b, a[1], acc2[1][nt]);
        }
    }

    #pragma unroll
    for (int m = 0; m < 2; ++m) {
        int r = row0 + m * 16 + (lane & 15);
        if (r >= M) continue;
        #pragma unroll
        for (int nt = 0; nt < 8; ++nt) {
            int c0 = nt * 16 + q * 4;
            fx4 bb = ld4(b2 + c0);
            f32x4 o = acc2[m][nt];
            #pragma unroll
            for (int j = 0; j < 4; ++j) o[j] += bb[j];
            if (OUTF) st4(outF + (size_t)r * 128 + c0, o);
            if (OUTB) *reinterpret_cast<us4v*>(&outB[(size_t)r * 128 + c0]) = pk4(o);
        }
    }
}

// ---- dual-output GEMM with K-SPLIT staging: LDS = 32KB (256 rows x 64 k) ----
// [O1|O2] = A[M][128] @ [Wa|Wb]; Wt 256 rows x 128k. Stage k-half, compute,
// restage. AF32: A fp32. BIAS2: add b0 to O1, b1 to O2.
template <bool AF32, bool BIAS2>
__global__ __launch_bounds__(256) void mfma_gemm_dual(
    const void* __restrict__ Av, const unsigned short* __restrict__ Wt,
    const float* __restrict__ b0, const float* __restrict__ b1,
    unsigned short* __restrict__ out1, unsigned short* __restrict__ out2, int M)
{
    __shared__ unsigned short Ws[256 * 64];     // 32 KB: one k-half of W
    const int tid = threadIdx.x;
    const int lane = tid & 63;
    const int wv = tid >> 6;
    const int row0 = blockIdx.x * 128 + wv * 32;

    const int ar = lane & 15;
    const int q = lane >> 4;
    const int ak = q * 8;

    f32x4 acc[2][16];
    #pragma unroll
    for (int m = 0; m < 2; ++m)
        #pragma unroll
        for (int nt = 0; nt < 16; ++nt) acc[m][nt] = {0.f, 0.f, 0.f, 0.f};

    #pragma unroll
    for (int khalf = 0; khalf < 2; ++khalf) {
        if (khalf) __syncthreads();             // all reads of prev half done
        // stage k-half: 256 rows x 8 chunks (16B), swizzled, row stride 64
        for (int i = tid; i < 256 * 8; i += 256) {
            int r = i >> 3, c8 = i & 7;
            *reinterpret_cast<us8*>(&Ws[r * 64 + ((c8 ^ (r & 7)) << 3)]) =
                *reinterpret_cast<const us8*>(
                    &Wt[(size_t)r * 128 + khalf * 64 + (c8 << 3)]);
        }
        __syncthreads();

        #pragma unroll
        for (int kk2 = 0; kk2 < 2; ++kk2) {
            const int kk = khalf * 2 + kk2;
            us8 a[2];
            loadA<128, AF32>(Av, row0, ar, ak, kk, M, a);
            const int lc = kk2 * 4 + q;         // local chunk 0..7
            #pragma unroll
            for (int nt = 0; nt < 16; ++nt) {
                int brow = nt * 16 + ar;
                us8 b = *reinterpret_cast<const us8*>(
                    &Ws[brow * 64 + ((lc ^ (brow & 7)) << 3)]);
                acc[0][nt] = mfma16(b, a[0], acc[0][nt]);
                acc[1][nt] = mfma16(b, a[1], acc[1][nt]);
            }
        }
    }

    #pragma unroll
    for (int m = 0; m < 2; ++m) {
        int r = row0 + m * 16 + (lane & 15);
        if (r >= M) continue;
        #pragma unroll
        for (int nt = 0; nt < 16; ++nt) {
            int c0 = (nt & 7) * 16 + q * 4;
            unsigned short* o = (nt < 8) ? out1 : out2;
            f32x4 v = acc[m][nt];
            if (BIAS2) {
                const float* bl = (nt < 8) ? b0 : b1;
                fx4 bb = ld4(bl + c0);
                #pragma unroll
                for (int j = 0; j < 4; ++j) v[j] += bb[j];
            }
            *reinterpret_cast<us4v*>(&o[(size_t)r * 128 + c0]) = pk4(v);
        }
    }
}

// ---------------- fp32 helper GEMM for the tiny weight-fold (M=128) ----------
__global__ __launch_bounds__(256) void gemm128_kernel(
    const float* __restrict__ X, const float* __restrict__ W,
    float* __restrict__ Out, int M)
{
    __shared__ float Xs[64 * 132];
    const int tid = threadIdx.x;
    const int row0 = blockIdx.x * 64;

    for (int i = tid; i < 64 * 32; i += 256) {
        int r = i >> 5, c = (i & 31) * 4;
        fx4 v = {0.f, 0.f, 0.f, 0.f};
        int gr = row0 + r;
        if (gr < M) v = ld4(X + (size_t)gr * 128 + c);
        st4(&Xs[r * 132 + c], v);
    }
    __syncthreads();

    const int ty = tid >> 4, tx = tid & 15;
    fx4 acc[4][2];
    #pragma unroll
    for (int r = 0; r < 4; ++r) { acc[r][0] = 0.f; acc[r][1] = 0.f; }
    for (int k = 0; k < 128; k += 4) {
        fx4 xr[4];
        #pragma unroll
        for (int r = 0; r < 4; ++r) xr[r] = ld4(&Xs[(ty * 4 + r) * 132 + k]);
        #pragma unroll
        for (int kk = 0; kk < 4; ++kk) {
            fx4 wa = ld4(W + (size_t)(k + kk) * 128 + tx * 8);
            fx4 wb = ld4(W + (size_t)(k + kk) * 128 + tx * 8 + 4);
            #pragma unroll
            for (int r = 0; r < 4; ++r) {
                acc[r][0] += xr[r][kk] * wa;
                acc[r][1] += xr[r][kk] * wb;
            }
        }
    }
    #pragma unroll
    for (int r = 0; r < 4; ++r) {
        int gr = row0 + ty * 4 + r;
        if (gr < M) {
            st4(Out + (size_t)gr * 128 + tx * 8, acc[r][0]);
            st4(Out + (size_t)gr * 128 + tx * 8 + 4, acc[r][1]);
        }
    }
}

// ---------------- weight prep ------------------------------------------------
struct TJob { const float* src; unsigned short* dst; int K; };
struct TJobs { TJob j[16]; };

__global__ __launch_bounds__(256) void transpose_kernel(TJobs jobs) {
    TJob t = jobs.j[blockIdx.x];
    int total = 128 * t.K;
    for (int i = threadIdx.x; i < total; i += 256) {
        int n = i / t.K, k = i - n * t.K;
        t.dst[(size_t)n * t.K + k] = f2bf(t.src[(size_t)k * 128 + n]);
    }
}

__global__ __launch_bounds__(128) void bep_kernel(
    const float* __restrict__ ee_b2, const float* __restrict__ ml_w1,
    const float* __restrict__ ml_b1, float* __restrict__ bep)
{
    int l = blockIdx.x, n = threadIdx.x;
    const float* W1b = ml_w1 + (size_t)l * 384 * 128 + 128 * 128;
    float s = ml_b1[(size_t)l * 128 + n];
    for (int k = 0; k < 128; ++k) s += ee_b2[k] * W1b[(size_t)k * 128 + n];
    bep[(size_t)l * 128 + n] = s;
}

// ---------------- CSR build --------------------------------------------------
__global__ __launch_bounds__(256) void csr_hist_kernel(
    const int* __restrict__ el, int* __restrict__ cnt, int NE)
{
    int e = blockIdx.x * 256 + threadIdx.x;
    if (e < NE) {
        atomicAdd(&cnt[el[2 * (size_t)e + 1]], 1);
        atomicAdd(&cnt[el[2 * (size_t)e]], 1);
    }
}

__global__ __launch_bounds__(256) void scan_p1_kernel(
    const int* __restrict__ cnt, int* __restrict__ bsum, int NN)
{
    __shared__ int red[256];
    const int t = threadIdx.x;
    int i = blockIdx.x * 256 + t;
    red[t] = (i < NN) ? cnt[i] : 0;
    __syncthreads();
    for (int off = 128; off > 0; off >>= 1) {
        if (t < off) red[t] += red[t + off];
        __syncthreads();
    }
    if (t == 0) bsum[blockIdx.x] = red[0];
}

__global__ __launch_bounds__(256) void scan_p2_kernel(
    int* __restrict__ bsum, int* __restrict__ startp, int nb, int NN)
{
    __shared__ int part[256];
    const int t = threadIdx.x;
    int v = (t < nb) ? bsum[t] : 0;
    part[t] = v;
    __syncthreads();
    for (int off = 1; off < 256; off <<= 1) {
        int u = (t >= off) ? part[t - off] : 0;
        __syncthreads();
        part[t] += u;
        __syncthreads();
    }
    if (t < nb) bsum[t] = part[t] - v;
    if (t == 255) startp[NN] = part[255];
}

__global__ __launch_bounds__(256) void scan_p3_kernel(
    int* __restrict__ cnt, const int* __restrict__ bsum,
    int* __restrict__ startp, int NN)
{
    __shared__ int part[256];
    const int t = threadIdx.x;
    int i = blockIdx.x * 256 + t;
    int v = (i < NN) ? cnt[i] : 0;
    part[t] = v;
    __syncthreads();
    for (int off = 1; off < 256; off <<= 1) {
        int u = (t >= off) ? part[t - off] : 0;
        __syncthreads();
        part[t] += u;
        __syncthreads();
    }
    if (i < NN) {
        startp[i] = bsum[blockIdx.x] + part[t] - v;
        cnt[i] = 0;
    }
}

__global__ __launch_bounds__(256) void csr_fill_kernel(
    const int* __restrict__ el, const int* __restrict__ startp,
    int* __restrict__ cursor, int2* __restrict__ inc, int NE)
{
    int e = blockIdx.x * 256 + threadIdx.x;
    if (e < NE) {
        int s = el[2 * (size_t)e], d = el[2 * (size_t)e + 1];
        int p = startp[d] + atomicAdd(&cursor[d], 1);
        inc[p] = make_int2(s, e);
        int q = startp[s] + atomicAdd(&cursor[s], 1);
        inc[q] = make_int2(d, e);
    }
}

// ---------------- gather: S[n] = sum_j relu(P1[o_j] + Ep[e_j] + P3[n]) -------
__global__ __launch_bounds__(256) void gather_kernel(
    const unsigned short* __restrict__ P1bf, const unsigned short* __restrict__ P3bf,
    const unsigned short* __restrict__ Ep, const int2* __restrict__ inc,
    const int* __restrict__ startp, unsigned short* __restrict__ S, int M)
{
    const int tid = threadIdx.x;
    const int lane = tid & 63;
    const int n = blockIdx.x * 4 + (tid >> 6);
    if (n >= M) return;
    const int slot = lane >> 4;
    const int c = (lane & 15) * 8;

    float p3[8], acc[8];
    us8 u3 = *reinterpret_cast<const us8*>(&P3bf[(size_t)n * 128 + c]);
    #pragma unroll
    for (int i = 0; i < 8; ++i) {
        p3[i] = bf2f((unsigned int)(unsigned short)u3[i]);
        acc[i] = 0.f;
    }

    const int j1 = startp[n + 1];
    int j = startp[n] + slot;
    int2 oe = (j < j1) ? inc[j] : make_int2(0, 0);
    while (j < j1) {
        int jn = j + 4;
        int2 oen = (jn < j1) ? inc[jn] : make_int2(0, 0);
        us8 u1 = *reinterpret_cast<const us8*>(&P1bf[(size_t)oe.x * 128 + c]);
        us8 ue = *reinterpret_cast<const us8*>(&Ep[(size_t)oe.y * 128 + c]);
        #pragma unroll
        for (int i = 0; i < 8; ++i)
            acc[i] += fmaxf(p3[i] + bf2f((unsigned int)(unsigned short)u1[i])
                                  + bf2f((unsigned int)(unsigned short)ue[i]), 0.f);
        j = jn; oe = oen;
    }

    #pragma unroll
    for (int i = 0; i < 8; ++i) {
        acc[i] += __shfl_xor(acc[i], 16, 64);
        acc[i] += __shfl_xor(acc[i], 32, 64);
    }
    if (slot == 0) {
        us8 pk;
        #pragma unroll
        for (int i = 0; i < 8; ++i) pk[i] = f2bf(acc[i]);
        *reinterpret_cast<us8*>(&S[(size_t)n * 128 + c]) = pk;
    }
}

// ---------------- host launch ------------------------------------------------
extern "C" void kernel_launch(void* const* d_in, const int* in_sizes, int n_in,
                              void* d_out, int out_size, void* d_ws, size_t ws_size,
                              hipStream_t stream) {
    const float* node_f    = (const float*)d_in[0];
    const int*   edge_list = (const int*)d_in[1];
    const float* edge_f    = (const float*)d_in[2];
    const float* ne_w1 = (const float*)d_in[4];
    const float* ne_b1 = (const float*)d_in[5];
    const float* ne_w2 = (const float*)d_in[6];
    const float* ne_b2 = (const float*)d_in[7];
    const float* ee_w1 = (const float*)d_in[8];
    const float* ee_b1 = (const float*)d_in[9];
    const float* ee_w2 = (const float*)d_in[10];
    const float* ee_b2 = (const float*)d_in[11];
    const float* ml_w1 = (const float*)d_in[12];
    const float* ml_b1 = (const float*)d_in[13];
    const float* ml_w2 = (const float*)d_in[14];
    const float* ml_b2 = (const float*)d_in[15];
    const float* agg_w1 = (const float*)d_in[16];
    const float* agg_b1 = (const float*)d_in[17];
    const float* agg_w2 = (const float*)d_in[18];
    const float* agg_b2 = (const float*)d_in[19];

    const int NN = in_sizes[0] / 128;
    const int NE = in_sizes[1] / 2;
    const int n_layers = in_sizes[12] / (384 * 128);

    char* p = (char*)d_ws;
    auto alloc = [&](size_t bytes) -> void* {
        void* r = (void*)p;
        p += (bytes + 255) & ~(size_t)255;
        return r;
    };
    float* node_emb = (float*)alloc((size_t)NN * 128 * 4);
    unsigned short* P1bf = (unsigned short*)alloc((size_t)NN * 128 * 2);
    unsigned short* P3bf = (unsigned short*)alloc((size_t)NN * 128 * 2);
    unsigned short* bufS = (unsigned short*)alloc((size_t)NN * 128 * 2);
    unsigned short* H_edge = (unsigned short*)alloc((size_t)NE * 128 * 2);
    unsigned short* Ep0 = (unsigned short*)alloc((size_t)NE * 128 * 2);
    unsigned short* Ep1 = (unsigned short*)alloc((size_t)NE * 128 * 2);
    unsigned short* ne_w1t = (unsigned short*)alloc(128 * 128 * 2);
    unsigned short* ne_w2t = (unsigned short*)alloc(128 * 128 * 2);
    unsigned short* ee_w1t = (unsigned short*)alloc(128 * 64 * 2);
    unsigned short* aw1t = (unsigned short*)alloc(128 * 128 * 2);
    unsigned short* aw2t = (unsigned short*)alloc(128 * 128 * 2);
    unsigned short* Wepct = (unsigned short*)alloc(256 * 128 * 2);  // [Wep0^T; Wep1^T]
    unsigned short* W13t[2], *W2t[2];
    float* Wepf[2];
    for (int l = 0; l < 2; ++l) {
        W13t[l] = (unsigned short*)alloc(256 * 128 * 2);
        W2t[l]  = (unsigned short*)alloc(128 * 128 * 2);
        Wepf[l] = (float*)alloc(128 * 128 * 4);
    }
    float* bep = (float*)alloc((size_t)2 * 128 * 4);
    int* cnt = (int*)alloc((size_t)NN * 4);
    int* startp = (int*)alloc((size_t)(NN + 1) * 4);
    int* bsum = (int*)alloc(256 * 4);
    int2* inc = (int2*)alloc((size_t)2 * NE * 8);
    size_t need = (size_t)(p - (char*)d_ws);
    if (ws_size < need) return;

    dim3 blk(256);
    const int gM_N = (NN + 127) / 128;
    const int gM_E = (NE + 127) / 128;
    const int gE256 = (NE + 255) / 256;
    const int nbScan = (NN + 255) / 256;

    // ---- weight prep ----
    for (int l = 0; l < n_layers && l < 2; ++l) {
        const float* W1b = ml_w1 + (size_t)l * 384 * 128 + 128 * 128;
        gemm128_kernel<<<2, blk, 0, stream>>>(ee_w2, W1b, Wepf[l], 128);
    }
    {
        TJobs jobs{};
        int nj = 0;
        jobs.j[nj++] = {ne_w1, ne_w1t, 128};
        jobs.j[nj++] = {ne_w2, ne_w2t, 128};
        jobs.j[nj++] = {ee_w1, ee_w1t, 64};
        jobs.j[nj++] = {agg_w1, aw1t, 128};
        jobs.j[nj++] = {agg_w2, aw2t, 128};
        for (int l = 0; l < n_layers && l < 2; ++l) {
            jobs.j[nj++] = {ml_w1 + (size_t)l * 384 * 128, W13t[l], 128};
            jobs.j[nj++] = {ml_w1 + (size_t)l * 384 * 128 + 256 * 128, W13t[l] + 128 * 128, 128};
            jobs.j[nj++] = {ml_w2 + (size_t)l * 128 * 128, W2t[l], 128};
        }
        jobs.j[nj++] = {Wepf[0], Wepct, 128};
        jobs.j[nj++] = {Wepf[(n_layers > 1) ? 1 : 0], Wepct + 128 * 128, 128};
        transpose_kernel<<<nj, blk, 0, stream>>>(jobs);
    }
    bep_kernel<<<n_layers, 128, 0, stream>>>(ee_b2, ml_w1, ml_b1, bep);

    // ---- encoders ----
    mfma_mlp<true, true, false><<<gM_N, blk, 0, stream>>>(
        node_f, ne_w1t, ne_b1, ne_w2t, ne_b2, node_emb, nullptr, NN);
    mfma_gemm<64, true, true, true, false, true, false><<<gM_E, blk, 0, stream>>>(
        edge_f, ee_w1t, ee_b1, nullptr, H_edge, nullptr, nullptr, NE);
    mfma_gemm_dual<false, true><<<gM_E, blk, 0, stream>>>(
        H_edge, Wepct, bep, bep + ((n_layers > 1) ? 128 : 0), Ep0, Ep1, NE);

    // ---- CSR incidence ----
    hipMemsetAsync(cnt, 0, (size_t)NN * sizeof(int), stream);
    csr_hist_kernel<<<gE256, blk, 0, stream>>>(edge_list, cnt, NE);
    scan_p1_kernel<<<nbScan, blk, 0, stream>>>(cnt, bsum, NN);
    scan_p2_kernel<<<1, blk, 0, stream>>>(bsum, startp, nbScan, NN);
    scan_p3_kernel<<<nbScan, blk, 0, stream>>>(cnt, bsum, startp, NN);
    csr_fill_kernel<<<gE256, blk, 0, stream>>>(edge_list, startp, cnt, inc, NE);

    float* out = (float*)d_out;
    for (int l = 0; l < n_layers && l < 2; ++l) {
        mfma_gemm_dual<true, false><<<gM_N, blk, 0, stream>>>(
            node_emb, W13t[l], nullptr, nullptr, P1bf, P3bf, NN);
        gather_kernel<<<(NN + 3) / 4, blk, 0, stream>>>(
            P1bf, P3bf, (l == 0) ? Ep0 : Ep1, inc, startp, bufS, NN);
        mfma_gemm<128, false, true, false, false, true, true><<<gM_N, blk, 0, stream>>>(
            bufS, W2t[l], ml_b2 + (size_t)l * 128, nullptr, P1bf, node_emb, startp, NN);
        float* dst = (l == n_layers - 1) ? out : node_emb;
        mfma_mlp<false, true, false><<<gM_N, blk, 0, stream>>>(
            P1bf, aw1t, agg_b1, aw2t, agg_b2, dst, nullptr, NN);
    }
}